// Round 7
// baseline (597.415 us; speedup 1.0000x reference)
//
#include <hip/hip_runtime.h>
#include <hip/hip_bf16.h>
#include <math.h>

#define D_FEAT 128
#define ALPHA 0.2f
#define EPS 1e-8f

typedef __bf16 bf16x8 __attribute__((ext_vector_type(8)));
typedef __bf16 bf16x2 __attribute__((ext_vector_type(2)));
typedef float f32x4 __attribute__((ext_vector_type(4)));
typedef float f32x2 __attribute__((ext_vector_type(2)));

// Split 8 consecutive f32 into hi/lo bf16 halves: x ~= hi + lo
__device__ __forceinline__ void split_bf16(const float* __restrict__ p,
                                           bf16x8& hi, bf16x8& lo)
{
    f32x4 a = *(const f32x4*)p;
    f32x4 b = *(const f32x4*)(p + 4);
#pragma unroll
    for (int j = 0; j < 4; ++j) {
        float x = a[j]; __bf16 xh = (__bf16)x;
        hi[j] = xh; lo[j] = (__bf16)(x - (float)xh);
        float y = b[j]; __bf16 yh = (__bf16)y;
        hi[j + 4] = yh; lo[j + 4] = (__bf16)(y - (float)yh);
    }
}

// ---------------------------------------------------------------------------
// K0: pre-split W (128x128 f32) into Whi/Wlo bf16 arrays (once per launch).
// ---------------------------------------------------------------------------
__global__ __launch_bounds__(256) void presplit_w(
    const float* __restrict__ W, __bf16* __restrict__ Whi, __bf16* __restrict__ Wlo)
{
    const int i = blockIdx.x * 256 + threadIdx.x;   // 64 blocks x 256 = 16384
    const float x = W[i];
    const __bf16 xh = (__bf16)x;
    Whi[i] = xh;
    Wlo[i] = (__bf16)(x - (float)xh);
}

// ---------------------------------------------------------------------------
// K1: Wh = h @ W^T via split-bf16 MFMA (f32-grade accumulators) + fused
// dst-histogram (grid exactly covers E at 4 edges/thread; the coalesced dst
// read + atomics hide under the MFMA work).
// ---------------------------------------------------------------------------
__global__ __launch_bounds__(256) void gemm_s_kernel(
    const float* __restrict__ h,
    const __bf16* __restrict__ Whi, const __bf16* __restrict__ Wlo,
    const float* __restrict__ a, __bf16* __restrict__ Whb,
    float* __restrict__ s_src, float* __restrict__ s_dst,
    const int* __restrict__ dst, int* __restrict__ count, int E, int N)
{
    // ---- fused histogram (grid-stride, 4 edges per thread) ----
    const int stride4 = gridDim.x * blockDim.x * 4;
    for (int base = (blockIdx.x * blockDim.x + threadIdx.x) * 4; base < E; base += stride4) {
        if (base + 3 < E) {
            const int4 d4 = *(const int4*)(dst + base);
            atomicAdd(count + d4.x, 1);
            atomicAdd(count + d4.y, 1);
            atomicAdd(count + d4.z, 1);
            atomicAdd(count + d4.w, 1);
        } else {
            for (int i = base; i < E; ++i) atomicAdd(count + dst[i], 1);
        }
    }

    const int wave = threadIdx.x >> 6;
    const int lane = threadIdx.x & 63;
    const int row0 = blockIdx.x * 64 + wave * 16;
    if (row0 >= N) return;

    const int l15 = lane & 15;
    const int quad = lane >> 4;

    int arow = row0 + l15;
    if (arow >= N) arow = N - 1;
    bf16x8 ahi[4], alo[4];
#pragma unroll
    for (int kk = 0; kk < 4; ++kk)
        split_bf16(h + (size_t)arow * D_FEAT + kk * 32 + quad * 8, ahi[kk], alo[kk]);

    f32x4 acc[8];
#pragma unroll
    for (int n = 0; n < 8; ++n) acc[n] = (f32x4){0.f, 0.f, 0.f, 0.f};

#pragma unroll
    for (int kk = 0; kk < 4; ++kk) {
#pragma unroll
        for (int n = 0; n < 8; ++n) {
            const size_t boff = (size_t)(n * 16 + l15) * D_FEAT + kk * 32 + quad * 8;
            const bf16x8 bhi = *(const bf16x8*)(Whi + boff);
            const bf16x8 blo = *(const bf16x8*)(Wlo + boff);
            acc[n] = __builtin_amdgcn_mfma_f32_16x16x32_bf16(ahi[kk], bhi, acc[n], 0, 0, 0);
            acc[n] = __builtin_amdgcn_mfma_f32_16x16x32_bf16(ahi[kk], blo, acc[n], 0, 0, 0);
            acc[n] = __builtin_amdgcn_mfma_f32_16x16x32_bf16(alo[kk], bhi, acc[n], 0, 0, 0);
        }
    }

    float psrc[4] = {0.f, 0.f, 0.f, 0.f};
    float pdst[4] = {0.f, 0.f, 0.f, 0.f};
#pragma unroll
    for (int n = 0; n < 8; ++n) {
        const int col = n * 16 + l15;
        const float as = a[col];
        const float ad = a[D_FEAT + col];
#pragma unroll
        for (int r = 0; r < 4; ++r) {
            const int row = row0 + quad * 4 + r;
            const float v = acc[n][r];
            if (row < N) Whb[(size_t)row * D_FEAT + col] = (__bf16)v;
            psrc[r] += v * as;
            pdst[r] += v * ad;
        }
    }
#pragma unroll
    for (int off = 1; off < 16; off <<= 1) {
#pragma unroll
        for (int r = 0; r < 4; ++r) {
            psrc[r] += __shfl_xor(psrc[r], off, 64);
            pdst[r] += __shfl_xor(pdst[r], off, 64);
        }
    }
    if (l15 == 0) {
#pragma unroll
        for (int r = 0; r < 4; ++r) {
            const int row = row0 + quad * 4 + r;
            if (row < N) { s_src[row] = psrc[r]; s_dst[row] = pdst[r]; }
        }
    }
}

// ---------------------------------------------------------------------------
// Single-block exclusive scan: count[0..N) -> row_ptr[0..N], cursor copy.
// 1024 threads, each owns a contiguous chunk; LDS Hillis-Steele over sums.
// ---------------------------------------------------------------------------
__global__ __launch_bounds__(1024) void scan_one(
    const int* __restrict__ count, int* __restrict__ row_ptr,
    int* __restrict__ cursor, int N, int E)
{
    __shared__ int sh[1024];
    const int t = threadIdx.x;
    const int chunk = (N + 1023) / 1024;
    const int lo = t * chunk;
    const int hi = min(lo + chunk, N);

    int ts = 0;
    for (int i = lo; i < hi; ++i) ts += count[i];
    sh[t] = ts;
    __syncthreads();
    for (int off = 1; off < 1024; off <<= 1) {
        int x = (t >= off) ? sh[t - off] : 0;
        __syncthreads();
        sh[t] += x;
        __syncthreads();
    }
    int run = sh[t] - ts;   // exclusive prefix
    for (int i = lo; i < hi; ++i) {
        row_ptr[i] = run;
        cursor[i] = run;
        run += count[i];
    }
    if (t == 1023) row_ptr[N] = E;
}

// ---------------------------------------------------------------------------
// comp_scatter: ex = exp(leaky(s_src[src]+s_dst[dst]) * w); scatter {src,ex}
// into dst-sorted CSR order. (No max-subtraction: softmax is shift-invariant
// and |e| <= ~6 here, so exp can't overflow.)
// ---------------------------------------------------------------------------
__global__ __launch_bounds__(256) void comp_scatter(
    const int* __restrict__ src, const int* __restrict__ dst,
    const float* __restrict__ ew,
    const float* __restrict__ s_src, const float* __restrict__ s_dst,
    int* __restrict__ cursor, uint2* __restrict__ sorted, int E)
{
    const int i = blockIdx.x * blockDim.x + threadIdx.x;
    if (i >= E) return;
    const int s = src[i], d = dst[i];
    float e = s_src[s] + s_dst[d];
    e = (e >= 0.f) ? e : ALPHA * e;
    e *= ew[i];
    const float ex = __expf(e);
    const int pos = atomicAdd(cursor + d, 1);
    sorted[pos] = make_uint2((unsigned)s, __float_as_uint(ex));
}

// ---------------------------------------------------------------------------
// K4: gather aggregation, one wave per node, no atomics.
// Edge metas live in registers (one per lane); phase 2 shuffle-broadcasts
// them so row-gather loads have no load->load dep chain; 4x unroll.
// ---------------------------------------------------------------------------
__global__ __launch_bounds__(256) void aggregate_csr(
    const int* __restrict__ row_ptr, const uint2* __restrict__ sorted,
    const __bf16* __restrict__ Whb, float* __restrict__ out, int N)
{
    const int wave = threadIdx.x >> 6;
    const int lane = threadIdx.x & 63;
    const int node = blockIdx.x * 4 + wave;
    if (node >= N) return;
    const int beg = row_ptr[node];
    const int end = row_ptr[node + 1];
    const int cnt = end - beg;

    int mx = 0; unsigned my = 0u;
    if (lane < cnt) {
        const uint2 m = sorted[beg + lane];
        mx = (int)m.x; my = m.y;
    }
    float ssum = (lane < cnt) ? __uint_as_float(my) : 0.f;
    for (int j = beg + 64 + lane; j < end; j += 64)
        ssum += __uint_as_float(sorted[j].y);
#pragma unroll
    for (int off = 1; off < 64; off <<= 1)
        ssum += __shfl_xor(ssum, off, 64);
    const float inv = 1.f / (ssum + EPS);

    const int c0 = lane * 2;
    const int inreg = cnt < 64 ? cnt : 64;
    float ax = 0.f, ay = 0.f;
    int j = 0;
    for (; j + 3 < inreg; j += 4) {
        const int s0 = __shfl(mx, j, 64);
        const int s1 = __shfl(mx, j + 1, 64);
        const int s2 = __shfl(mx, j + 2, 64);
        const int s3 = __shfl(mx, j + 3, 64);
        const float a0 = __uint_as_float((unsigned)__shfl((int)my, j, 64)) * inv;
        const float a1 = __uint_as_float((unsigned)__shfl((int)my, j + 1, 64)) * inv;
        const float a2 = __uint_as_float((unsigned)__shfl((int)my, j + 2, 64)) * inv;
        const float a3 = __uint_as_float((unsigned)__shfl((int)my, j + 3, 64)) * inv;
        const bf16x2 v0 = *(const bf16x2*)(Whb + (size_t)s0 * D_FEAT + c0);
        const bf16x2 v1 = *(const bf16x2*)(Whb + (size_t)s1 * D_FEAT + c0);
        const bf16x2 v2 = *(const bf16x2*)(Whb + (size_t)s2 * D_FEAT + c0);
        const bf16x2 v3 = *(const bf16x2*)(Whb + (size_t)s3 * D_FEAT + c0);
        ax += a0 * (float)v0[0] + a1 * (float)v1[0] + a2 * (float)v2[0] + a3 * (float)v3[0];
        ay += a0 * (float)v0[1] + a1 * (float)v1[1] + a2 * (float)v2[1] + a3 * (float)v3[1];
    }
    for (; j < inreg; ++j) {
        const int s0 = __shfl(mx, j, 64);
        const float a0 = __uint_as_float((unsigned)__shfl((int)my, j, 64)) * inv;
        const bf16x2 v0 = *(const bf16x2*)(Whb + (size_t)s0 * D_FEAT + c0);
        ax += a0 * (float)v0[0];
        ay += a0 * (float)v0[1];
    }
    for (int jj = beg + 64; jj < end; ++jj) {
        const uint2 m = sorted[jj];
        const float a0 = __uint_as_float(m.y) * inv;
        const bf16x2 v0 = *(const bf16x2*)(Whb + (size_t)m.x * D_FEAT + c0);
        ax += a0 * (float)v0[0];
        ay += a0 * (float)v0[1];
    }
    f32x2 r; r[0] = ax; r[1] = ay;
    *(f32x2*)(out + (size_t)node * D_FEAT + c0) = r;
}

extern "C" void kernel_launch(void* const* d_in, const int* in_sizes, int n_in,
                              void* d_out, int out_size, void* d_ws, size_t ws_size,
                              hipStream_t stream) {
    const float* h  = (const float*)d_in[0];
    const int* eidx = (const int*)d_in[1];
    const float* ew = (const float*)d_in[2];
    const float* W  = (const float*)d_in[3];
    const float* a  = (const float*)d_in[4];
    float* out      = (float*)d_out;

    const int N = in_sizes[0] / D_FEAT;     // 100000
    const int E = in_sizes[2];              // 1600000
    const int* src = eidx;
    const int* dst = eidx + E;

    // workspace layout
    char* ws = (char*)d_ws;
    size_t off = 0;
    int*    count     = (int*)(ws + off);   off += (size_t)N * 4;
    int*    cursor    = (int*)(ws + off);   off += (size_t)N * 4;
    float*  s_src     = (float*)(ws + off); off += (size_t)N * 4;
    float*  s_dst     = (float*)(ws + off); off += (size_t)N * 4;
    int*    row_ptr   = (int*)(ws + off);   off += (size_t)(N + 1) * 4;
    off = (off + 15) & ~(size_t)15;
    __bf16* Whi       = (__bf16*)(ws + off); off += (size_t)D_FEAT * D_FEAT * 2;
    __bf16* Wlo       = (__bf16*)(ws + off); off += (size_t)D_FEAT * D_FEAT * 2;
    uint2*  sorted    = (uint2*)(ws + off);  off += (size_t)E * 8;          // 12.8 MB
    __bf16* Whb       = (__bf16*)(ws + off); off += (size_t)N * D_FEAT * 2; // 25.6 MB

    hipMemsetAsync(count, 0, (size_t)N * 4, stream);

    presplit_w<<<64, 256, 0, stream>>>(W, Whi, Wlo);
    gemm_s_kernel<<<(N + 63) / 64, 256, 0, stream>>>(h, Whi, Wlo, a, Whb,
                                                     s_src, s_dst, dst, count, E, N);
    scan_one<<<1, 1024, 0, stream>>>(count, row_ptr, cursor, N, E);
    comp_scatter<<<(E + 255) / 256, 256, 0, stream>>>(src, dst, ew, s_src, s_dst,
                                                      cursor, sorted, E);
    aggregate_csr<<<(N + 3) / 4, 256, 0, stream>>>(row_ptr, sorted, Whb, out, N);
}